// Round 8
// baseline (539.928 us; speedup 1.0000x reference)
//
#include <hip/hip_runtime.h>

#define B_DIM 512
#define R_DIM 1152
#define C_DIM 10
#define CO    160   // C*O = 10*16
#define NCO4  40    // CO/4
#define NCH   64    // r-chunks
#define RPC   18    // r's per chunk (64*18 = 1152)

// xor-mask lane swizzle within 32-lane halves (BitMode: offset = xor<<10 | 0x1F)
#define SWZ(v, mask) __int_as_float(__builtin_amdgcn_ds_swizzle(__float_as_int(v), 0x1F | ((mask) << 10)))

// u4 for one (b,r): outputs co4*4..co4*4+3, reduced over i=8
__device__ __forceinline__ float4 einsum8(const float* w, const float* xr)
{
    float4 acc = make_float4(0.f, 0.f, 0.f, 0.f);
    #pragma unroll
    for (int i = 0; i < 8; ++i) {
        acc.x = fmaf(w[i],      xr[i], acc.x);
        acc.y = fmaf(w[8 + i],  xr[i], acc.y);
        acc.z = fmaf(w[16 + i], xr[i], acc.z);
        acc.w = fmaf(w[24 + i], xr[i], acc.w);
    }
    return acc;
}

// ---------------------------------------------------------------------------
// K1: part[ch][b][co] = sum_{r in chunk} u_hat[b,r,co].  Barrier-free.
// grid (16, 64) x block 256 (4 waves); wave = 8 b's x 18 r's.
// launch_bounds (256,4): VGPR cap 128 >= ~95 live -> no remat/reload.
// ---------------------------------------------------------------------------
__global__ __launch_bounds__(256, 4)
void k_sum(const float* __restrict__ x, const float* __restrict__ W,
           float* __restrict__ part)
{
    const int lane = threadIdx.x & 63;
    const int wv   = threadIdx.x >> 6;
    const int co4  = (lane < NCO4) ? lane : lane - NCO4;
    const int b0   = (blockIdx.x * 4 + wv) * 8;
    const int r0   = blockIdx.y * RPC;

    const float* wp = W + (size_t)r0 * (CO * 8) + co4 * 32;
    const float* xp[8];
    #pragma unroll
    for (int bb = 0; bb < 8; ++bb)
        xp[bb] = x + ((size_t)(b0 + bb) * R_DIM + r0) * 8;

    float4 sacc[8];
    #pragma unroll
    for (int i = 0; i < 8; ++i) sacc[i] = make_float4(0.f, 0.f, 0.f, 0.f);

    for (int rr = 0; rr < RPC; ++rr) {
        float w[32];
        #pragma unroll
        for (int k = 0; k < 8; ++k)
            *reinterpret_cast<float4*>(&w[k * 4]) =
                *reinterpret_cast<const float4*>(wp + k * 4);
        #pragma unroll
        for (int bb = 0; bb < 8; ++bb) {
            float xr[8];
            *reinterpret_cast<float4*>(&xr[0]) = *reinterpret_cast<const float4*>(xp[bb]);
            *reinterpret_cast<float4*>(&xr[4]) = *reinterpret_cast<const float4*>(xp[bb] + 4);
            xp[bb] += 8;
            float4 u4 = einsum8(w, xr);
            sacc[bb].x += u4.x; sacc[bb].y += u4.y;
            sacc[bb].z += u4.z; sacc[bb].w += u4.w;
        }
        wp += CO * 8;
    }
    if (lane < NCO4) {
        #pragma unroll
        for (int bb = 0; bb < 8; ++bb)
            *reinterpret_cast<float4*>(
                part + ((size_t)blockIdx.y * B_DIM + b0 + bb) * CO + co4 * 4) = sacc[bb];
    }
}

// ---------------------------------------------------------------------------
// Routing pass, barrier-free, swizzle softmax WITHOUT max-subtraction
// (logits = u.v bounded: |v|<1 -> sigma<=~6, exp overflow at 88 impossible).
// vl = v1 (PASS 1) or v1+v2 (PASS 2; b_ij eliminated: a1+a2 = u.(v1+v2)).
// NB=4 b's/wave (VGPR ~95 <= 128 cap), grid 2048 blocks (8/CU, 4 resident).
// Quad xor{1,2}: o-dot -> a[c].  Z: xor{4,8,16} in-half + xor32 cross-half;
// stride-4 classes: half-1 sums c=0..7, half-2 c=8,9 (+ e=0 dups), xor32
// completes sum over all 10 c's on every lane.
// ---------------------------------------------------------------------------
template<int PASS>
__global__ __launch_bounds__(256, 4)
void k_pass(const float* __restrict__ x, const float* __restrict__ W,
            const float* __restrict__ v1, const float* __restrict__ v2,
            float* __restrict__ part)
{
    const int lane = threadIdx.x & 63;
    const int wv   = threadIdx.x >> 6;
    const int co4  = (lane < NCO4) ? lane : lane - NCO4;
    const int b0   = (blockIdx.x * 4 + wv) * 4;
    const int r0   = blockIdx.y * RPC;

    float4 vl[4];
    #pragma unroll
    for (int bb = 0; bb < 4; ++bb) {
        float4 a = *reinterpret_cast<const float4*>(
            v1 + (size_t)(b0 + bb) * CO + co4 * 4);
        if constexpr (PASS == 2) {
            float4 b2 = *reinterpret_cast<const float4*>(
                v2 + (size_t)(b0 + bb) * CO + co4 * 4);
            a.x += b2.x; a.y += b2.y; a.z += b2.z; a.w += b2.w;
        }
        vl[bb] = a;
    }

    const float* wp = W + (size_t)r0 * (CO * 8) + co4 * 32;
    const float* xp[4];
    #pragma unroll
    for (int bb = 0; bb < 4; ++bb)
        xp[bb] = x + ((size_t)(b0 + bb) * R_DIM + r0) * 8;

    float4 sacc[4];
    #pragma unroll
    for (int i = 0; i < 4; ++i) sacc[i] = make_float4(0.f, 0.f, 0.f, 0.f);

    for (int rr = 0; rr < RPC; ++rr) {
        float w[32];
        #pragma unroll
        for (int k = 0; k < 8; ++k)
            *reinterpret_cast<float4*>(&w[k * 4]) =
                *reinterpret_cast<const float4*>(wp + k * 4);
        #pragma unroll
        for (int bb = 0; bb < 4; ++bb) {
            float xr[8];
            *reinterpret_cast<float4*>(&xr[0]) = *reinterpret_cast<const float4*>(xp[bb]);
            *reinterpret_cast<float4*>(&xr[4]) = *reinterpret_cast<const float4*>(xp[bb] + 4);
            xp[bb] += 8;
            float4 u4 = einsum8(w, xr);

            float p = u4.x * vl[bb].x + u4.y * vl[bb].y
                    + u4.z * vl[bb].z + u4.w * vl[bb].w;
            p += SWZ(p, 1);
            p += SWZ(p, 2);                   // a[c] on all 4 quad lanes

            float e = (lane < NCO4) ? __expf(p) : 0.f;
            float Z = e;
            Z += SWZ(Z, 4);
            Z += SWZ(Z, 8);
            Z += SWZ(Z, 16);
            Z += __shfl_xor(Z, 32);           // full sum_c exp(a_c)

            const float cij = __fdividef(e, Z);
            sacc[bb].x += cij * u4.x; sacc[bb].y += cij * u4.y;
            sacc[bb].z += cij * u4.z; sacc[bb].w += cij * u4.w;
        }
        wp += CO * 8;
    }

    if (lane < NCO4) {
        #pragma unroll
        for (int bb = 0; bb < 4; ++bb)
            *reinterpret_cast<float4*>(
                part + ((size_t)blockIdx.y * B_DIM + b0 + bb) * CO + co4 * 4) = sacc[bb];
    }
}

// ---------------------------------------------------------------------------
// Reduce NCH chunk partials -> s, scale, squash over O=16, write dst.
// 81920 outputs: grid 320 x block 256; 16-lane groups = o 0..15 of one (b,c).
// ---------------------------------------------------------------------------
__global__ __launch_bounds__(256)
void k_vred(const float* __restrict__ part, float* __restrict__ dst,
            int nchunk, float scale)
{
    const int idx = blockIdx.x * 256 + threadIdx.x;
    const int b = idx / CO, co = idx % CO;
    float s = 0.f;
    for (int k = 0; k < nchunk; ++k)
        s += part[((size_t)k * B_DIM + b) * CO + co];
    s *= scale;
    float sq = s * s;
    sq += SWZ(sq, 1);
    sq += SWZ(sq, 2);
    sq += SWZ(sq, 4);
    sq += SWZ(sq, 8);
    float v = s * (sq / (1.f + sq)) / sqrtf(sq + 1e-8f);
    dst[idx] = v;
}

// ---------------------------------------------------------------------------
extern "C" void kernel_launch(void* const* d_in, const int* in_sizes, int n_in,
                              void* d_out, int out_size, void* d_ws, size_t ws_size,
                              hipStream_t stream)
{
    const float* x = (const float*)d_in[0];   // [512,1152,8]
    const float* W = (const float*)d_in[1];   // [1,1152,10,16,8]
    float* out = (float*)d_out;               // [512,10,16]
    float* ws  = (float*)d_ws;

    const size_t NP = (size_t)NCH * B_DIM * CO;   // 5,242,880 fl per partial
    const size_t NV = (size_t)B_DIM * CO;         // 81,920 fl per v
    if (ws_size < (3 * NP + 2 * NV) * 4) return;  // 63.6 MB (proven to fit)

    float* part1 = ws;
    float* part2 = part1 + NP;
    float* part3 = part2 + NP;
    float* v1    = part3 + NP;
    float* v2    = v1    + NV;

    const dim3 GS(16, NCH), GP(32, NCH), T(256), GV(320);
    k_sum    <<<GS, T, 0, stream>>>(x, W, part1);
    k_vred   <<<GV, T, 0, stream>>>(part1, v1, NCH, 0.1f);
    k_pass<1><<<GP, T, 0, stream>>>(x, W, v1, v1, part2);
    k_vred   <<<GV, T, 0, stream>>>(part2, v2, NCH, 1.0f);
    k_pass<2><<<GP, T, 0, stream>>>(x, W, v1, v2, part3);
    k_vred   <<<GV, T, 0, stream>>>(part3, out, NCH, 1.0f);
}

// Round 11
// 435.231 us; speedup vs baseline: 1.2406x; 1.2406x over previous
//
#include <hip/hip_runtime.h>

#define B_DIM 512
#define R_DIM 1152
#define C_DIM 10
#define CO    160   // C*O = 10*16
#define NCO4  40    // CO/4
#define NCH   96    // r-chunks  (96 x 12 = 1152)
#define RPC   12    // r's per chunk

// u4 for one (b,r): outputs co4*4..co4*4+3, reduced over i=8
__device__ __forceinline__ float4 einsum8(const float* w, const float* xr)
{
    float4 acc = make_float4(0.f, 0.f, 0.f, 0.f);
    #pragma unroll
    for (int i = 0; i < 8; ++i) {
        acc.x = fmaf(w[i],      xr[i], acc.x);
        acc.y = fmaf(w[8 + i],  xr[i], acc.y);
        acc.z = fmaf(w[16 + i], xr[i], acc.z);
        acc.w = fmaf(w[24 + i], xr[i], acc.w);
    }
    return acc;
}

// ---------------------------------------------------------------------------
// K1: part[ch][b][co] = sum_{r in chunk} u_hat[b,r,co].  Barrier-free.
// grid (16, 96) x block 256 (4 waves); wave = 8 b's x 12 r's.  6144 waves.
// Lanes 0..39 own co4 = lane; lanes 40..63 duplicate (never write).
// ---------------------------------------------------------------------------
__global__ __launch_bounds__(256)
void k_sum(const float* __restrict__ x, const float* __restrict__ W,
           float* __restrict__ part)
{
    const int lane = threadIdx.x & 63;
    const int wv   = __builtin_amdgcn_readfirstlane((int)(threadIdx.x >> 6));
    const int co4  = (lane < NCO4) ? lane : lane - NCO4;
    const int b0   = (blockIdx.x * 4 + wv) * 8;
    const int r0   = blockIdx.y * RPC;

    const float* wp = W + (size_t)r0 * (CO * 8) + co4 * 32;
    float4 sacc[8];
    #pragma unroll
    for (int i = 0; i < 8; ++i) sacc[i] = make_float4(0.f, 0.f, 0.f, 0.f);

    for (int rr = 0; rr < RPC; ++rr) {
        float w[32];
        #pragma unroll
        for (int k = 0; k < 8; ++k)
            *reinterpret_cast<float4*>(&w[k * 4]) =
                *reinterpret_cast<const float4*>(wp + k * 4);
        #pragma unroll
        for (int bb = 0; bb < 8; ++bb) {
            const float* xq = x + ((size_t)(b0 + bb) * R_DIM + r0 + rr) * 8;
            float xr[8];
            *reinterpret_cast<float4*>(&xr[0]) = *reinterpret_cast<const float4*>(xq);
            *reinterpret_cast<float4*>(&xr[4]) = *reinterpret_cast<const float4*>(xq + 4);
            float4 u4 = einsum8(w, xr);
            sacc[bb].x += u4.x; sacc[bb].y += u4.y;
            sacc[bb].z += u4.z; sacc[bb].w += u4.w;
        }
        wp += CO * 8;
    }
    if (lane < NCO4) {
        #pragma unroll
        for (int bb = 0; bb < 8; ++bb)
            *reinterpret_cast<float4*>(
                part + ((size_t)blockIdx.y * B_DIM + b0 + bb) * CO + co4 * 4) = sacc[bb];
    }
}

// ---------------------------------------------------------------------------
// Routing pass, barrier-free, shuffle softmax without max-subtraction
// (logits p = u.(v1[+v2]) bounded |p| <~ 50 << 88 exp-overflow; validated
// on HW in rounds 7-8 at absmax 2e-3).
// vl = v1 (PASS 1) or v1+v2 (PASS 2; b_ij eliminated: a1+a2 = u.(v1+v2)).
// NB=8 b's/wave (8 indep chains between W-gathers), grid (16,96), 6144 waves.
// Quad xor{1,2}: o-dot -> a[c].  Z: xor{4,8,16,32}: stride-4 classes hold one
// lane per c (dup lanes >=40 contribute e=0) -> exact sum_c on every lane.
// ---------------------------------------------------------------------------
template<int PASS>
__global__ __launch_bounds__(256)
void k_pass(const float* __restrict__ x, const float* __restrict__ W,
            const float* __restrict__ v1, const float* __restrict__ v2,
            float* __restrict__ part)
{
    const int lane = threadIdx.x & 63;
    const int wv   = __builtin_amdgcn_readfirstlane((int)(threadIdx.x >> 6));
    const int co4  = (lane < NCO4) ? lane : lane - NCO4;
    const int b0   = (blockIdx.x * 4 + wv) * 8;
    const int r0   = blockIdx.y * RPC;

    float4 vl[8];
    #pragma unroll
    for (int bb = 0; bb < 8; ++bb) {
        float4 a = *reinterpret_cast<const float4*>(
            v1 + (size_t)(b0 + bb) * CO + co4 * 4);
        if constexpr (PASS == 2) {
            float4 b2 = *reinterpret_cast<const float4*>(
                v2 + (size_t)(b0 + bb) * CO + co4 * 4);
            a.x += b2.x; a.y += b2.y; a.z += b2.z; a.w += b2.w;
        }
        vl[bb] = a;
    }

    float4 sacc[8];
    #pragma unroll
    for (int i = 0; i < 8; ++i) sacc[i] = make_float4(0.f, 0.f, 0.f, 0.f);

    const float* wp = W + (size_t)r0 * (CO * 8) + co4 * 32;
    for (int rr = 0; rr < RPC; ++rr) {
        float w[32];
        #pragma unroll
        for (int k = 0; k < 8; ++k)
            *reinterpret_cast<float4*>(&w[k * 4]) =
                *reinterpret_cast<const float4*>(wp + k * 4);
        #pragma unroll
        for (int bb = 0; bb < 8; ++bb) {
            const float* xq = x + ((size_t)(b0 + bb) * R_DIM + r0 + rr) * 8;
            float xr[8];
            *reinterpret_cast<float4*>(&xr[0]) = *reinterpret_cast<const float4*>(xq);
            *reinterpret_cast<float4*>(&xr[4]) = *reinterpret_cast<const float4*>(xq + 4);
            float4 u4 = einsum8(w, xr);

            float p = u4.x * vl[bb].x + u4.y * vl[bb].y
                    + u4.z * vl[bb].z + u4.w * vl[bb].w;
            p += __shfl_xor(p, 1);
            p += __shfl_xor(p, 2);            // a[c] on all 4 quad lanes

            float e = (lane < NCO4) ? __expf(p) : 0.f;
            float Z = e;
            Z += __shfl_xor(Z, 4);
            Z += __shfl_xor(Z, 8);
            Z += __shfl_xor(Z, 16);
            Z += __shfl_xor(Z, 32);           // exact sum_c exp(a_c)

            const float cij = __fdividef(e, Z);
            sacc[bb].x += cij * u4.x; sacc[bb].y += cij * u4.y;
            sacc[bb].z += cij * u4.z; sacc[bb].w += cij * u4.w;
        }
        wp += CO * 8;
    }

    if (lane < NCO4) {
        #pragma unroll
        for (int bb = 0; bb < 8; ++bb)
            *reinterpret_cast<float4*>(
                part + ((size_t)blockIdx.y * B_DIM + b0 + bb) * CO + co4 * 4) = sacc[bb];
    }
}

// ---------------------------------------------------------------------------
// Reduce NCH chunk partials -> s, scale, squash over O=16, write dst.
// 81920 outputs: grid 320 x block 256; 16-lane groups = o 0..15 of one (b,c).
// ---------------------------------------------------------------------------
__global__ __launch_bounds__(256)
void k_vred(const float* __restrict__ part, float* __restrict__ dst,
            int nchunk, float scale)
{
    const int idx = blockIdx.x * 256 + threadIdx.x;
    const int b = idx / CO, co = idx % CO;
    float s = 0.f;
    for (int k = 0; k < nchunk; ++k)
        s += part[((size_t)k * B_DIM + b) * CO + co];
    s *= scale;
    float sq = s * s;
    sq += __shfl_xor(sq, 1);
    sq += __shfl_xor(sq, 2);
    sq += __shfl_xor(sq, 4);
    sq += __shfl_xor(sq, 8);
    float v = s * (sq / (1.f + sq)) / sqrtf(sq + 1e-8f);
    dst[idx] = v;
}

// ---------------------------------------------------------------------------
// Buffer reuse: partA -> v1; partB -> v2; partA (overwrite) -> out.
// ws need = (2*NP + 2*NV)*4 = 63,569,920 B — bit-identical to the size
// proven to fit in rounds 6-8.
// ---------------------------------------------------------------------------
extern "C" void kernel_launch(void* const* d_in, const int* in_sizes, int n_in,
                              void* d_out, int out_size, void* d_ws, size_t ws_size,
                              hipStream_t stream)
{
    const float* x = (const float*)d_in[0];   // [512,1152,8]
    const float* W = (const float*)d_in[1];   // [1,1152,10,16,8]
    float* out = (float*)d_out;               // [512,10,16]
    float* ws  = (float*)d_ws;

    const size_t NP = (size_t)NCH * B_DIM * CO;   // 7,864,320 floats
    const size_t NV = (size_t)B_DIM * CO;         // 81,920 floats
    if (ws_size < (2 * NP + 2 * NV) * 4) return;  // 63.6 MB, proven to fit

    float* partA = ws;
    float* partB = partA + NP;
    float* v1    = partB + NP;
    float* v2    = v1    + NV;

    const dim3 G(16, NCH), T(256), GV(320);
    k_sum    <<<G, T, 0, stream>>>(x, W, partA);
    k_vred   <<<GV, T, 0, stream>>>(partA, v1, NCH, 0.1f);
    k_pass<1><<<G, T, 0, stream>>>(x, W, v1, v1, partB);
    k_vred   <<<GV, T, 0, stream>>>(partB, v2, NCH, 1.0f);
    k_pass<2><<<G, T, 0, stream>>>(x, W, v1, v2, partA);
    k_vred   <<<GV, T, 0, stream>>>(partA, out, NCH, 1.0f);
}